// Round 6
// baseline (176.278 us; speedup 1.0000x reference)
//
#include <hip/hip_runtime.h>

#define CH   128
#define KS   7
#define R    49
#define HH   56
#define NPOS 3136
#define BS   8
#define XSTR 401408
#define XTOT (BS*XSTR)

typedef short short8 __attribute__((ext_vector_type(8)));
typedef float f32x4  __attribute__((ext_vector_type(4)));
typedef unsigned int u32;
typedef u32 u32x4 __attribute__((ext_vector_type(4)));

__device__ __forceinline__ short f2bf(float f) {            // RNE fp32->bf16
    unsigned u = __float_as_uint(f);
    u += 0x7fffu + ((u >> 16) & 1u);
    return (short)(u >> 16);
}
__device__ __forceinline__ float bf2f(short s) {
    return __uint_as_float(((unsigned)(unsigned short)s) << 16);
}
__device__ __forceinline__ float bf2f_u(u32 lo16) {
    return __uint_as_float(lo16 << 16);
}

#define HSTR 136            // hid LDS row stride (bf16 elems)
#define PSTR 132            // P LDS row stride (fp32)
#define WGT_PP 3200         // u32 per pos: 25 j-pairs * 128 ch

// ---------- prep: W2 (fp32 [m][ch]) -> W2^T hi/lo bf16 ([ch][m]) ----------
__global__ __launch_bounds__(256) void poatt_prep(
    const float* __restrict__ W2, short* __restrict__ wsH, short* __restrict__ wsL)
{
    int t = blockIdx.x * 256 + threadIdx.x;
    int k = t >> 7, ch = t & 127;
    float w = W2[k * CH + ch];
    short hi = f2bf(w);
    wsH[ch * CH + k] = hi;
    wsL[ch * CH + k] = f2bf(w - bf2f(hi));
}

// ---------- cvt: x fp32 -> bf16 (8 elems/thread) ----------
__global__ __launch_bounds__(256) void poatt_cvt(
    const float* __restrict__ x, u32* __restrict__ x2)
{
    int t = blockIdx.x * 256 + threadIdx.x;      // 1568 blocks -> 401408 threads
    const float4* xv = reinterpret_cast<const float4*>(x);
    float4 a = xv[2 * t], b = xv[2 * t + 1];
    u32x4 o;
    o[0] = (u32)(unsigned short)f2bf(a.x) | ((u32)(unsigned short)f2bf(a.y) << 16);
    o[1] = (u32)(unsigned short)f2bf(a.z) | ((u32)(unsigned short)f2bf(a.w) << 16);
    o[2] = (u32)(unsigned short)f2bf(b.x) | ((u32)(unsigned short)f2bf(b.y) << 16);
    o[3] = (u32)(unsigned short)f2bf(b.z) | ((u32)(unsigned short)f2bf(b.w) << 16);
    reinterpret_cast<u32x4*>(x2)[t] = o;
}

// ---------- kernel A: softmax weights per pos -> packed bf16 [pos][j][ch] ----------
__global__ __launch_bounds__(256, 4) void poatt_wgt(
    const float* __restrict__ W1, const float* __restrict__ b1,
    const short* __restrict__ wsH, const short* __restrict__ wsL,
    u32* __restrict__ wgt)
{
    __shared__ float rel_s[R][2];
    __shared__ float ex_s[2][2][CH];
    __shared__ __align__(16) char smem[2 * 64 * HSTR * 2];   // 34816 B
    short* hidH = (short*)smem;
    short* hidL = hidH + 64 * HSTR;
    float* Pbuf = (float*)smem;                 // overlay after MFMA

    const int pos = blockIdx.x;
    const int tid = threadIdx.x;
    const int ch  = tid & (CH - 1);
    const int g   = tid >> 7;

    const int q  = pos >> 6;
    const int ii = q / KS;
    const int jj = q % KS;

    // phase 0: rel
    if (tid < 2 * R) {
        const int e  = (tid >= R) ? 1 : 0;
        const int rr = tid - e * R;
        int F  = (pos * 2 + e) * R + rr;
        int ep = F & 1;
        int t  = F >> 1;
        int jp = t % HH; t /= HH;
        int a  = t % HH; t /= HH;
        int jc = t % KS;
        int ic = t / KS;
        int row = jp + ic - 3;
        int col = ep + jc - 3;
        float v = 0.0f;
        if (row >= 0 && row < HH && (col == 0 || col == 1)) {
            int f    = a * (HH * 2) + row * 2 + col;
            int cidx = f / NPOS;
            int p    = f - cidx * NPOS;
            int u    = (cidx == 0) ? (p / HH) : (p % HH);
            v = -3.0f + 6.0f * (float)u * (1.0f / 55.0f);
        }
        const float c0 = -3.0f + 6.0f * (float)(pos / HH) * (1.0f / 55.0f);
        const float c1 = -3.0f + 6.0f * (float)(pos % HH) * (1.0f / 55.0f);
        rel_s[rr][e] = v - ((e == 0) ? c0 : c1);
    }
    __syncthreads();

    // phase 1: hid = relu(rel@W1+b1) -> bf16 hi/lo LDS
    {
        const float w10 = W1[ch];
        const float w11 = W1[CH + ch];
        const float bb  = b1[ch];
        for (int rr = g; rr < R; rr += 2) {
            float h = fmaf(rel_s[rr][0], w10, fmaf(rel_s[rr][1], w11, bb));
            h = fmaxf(h, 0.0f);
            short hi = f2bf(h);
            hidH[rr * HSTR + ch] = hi;
            hidL[rr * HSTR + ch] = f2bf(h - bf2f(hi));
        }
        for (int t = tid; t < 15 * HSTR; t += 256) {
            hidH[R * HSTR + t] = 0;
            hidL[R * HSTR + t] = 0;
        }
    }
    __syncthreads();

    // phase 2: P = hid @ W2 (3-term hi/lo bf16 MFMA)
    {
        const int w  = tid >> 6;
        const int l  = tid & 63;
        const int lr = l & 15;
        const int kg = l >> 4;

        short8 aH[4], aL[4];
        const int abase = (16 * w + lr) * HSTR + kg * 8;
        #pragma unroll
        for (int kk = 0; kk < 4; ++kk) {
            aH[kk] = *reinterpret_cast<const short8*>(&hidH[abase + kk * 32]);
            aL[kk] = *reinterpret_cast<const short8*>(&hidL[abase + kk * 32]);
        }

        f32x4 acc[8];
        #pragma unroll
        for (int n = 0; n < 8; ++n) acc[n] = (f32x4)0.0f;

        #pragma unroll
        for (int n = 0; n < 8; ++n) {
            const int bcol = 16 * n + lr;
            #pragma unroll
            for (int kk = 0; kk < 4; ++kk) {
                short8 bH = *reinterpret_cast<const short8*>(wsH + bcol * CH + kk * 32 + kg * 8);
                short8 bL = *reinterpret_cast<const short8*>(wsL + bcol * CH + kk * 32 + kg * 8);
                acc[n] = __builtin_amdgcn_mfma_f32_16x16x32_bf16(aL[kk], bH, acc[n], 0, 0, 0);
                acc[n] = __builtin_amdgcn_mfma_f32_16x16x32_bf16(aH[kk], bL, acc[n], 0, 0, 0);
                acc[n] = __builtin_amdgcn_mfma_f32_16x16x32_bf16(aH[kk], bH, acc[n], 0, 0, 0);
            }
        }
        __syncthreads();

        #pragma unroll
        for (int n = 0; n < 8; ++n) {
            #pragma unroll
            for (int r = 0; r < 4; ++r) {
                int rr = 16 * w + kg * 4 + r;
                if (rr < R) Pbuf[rr * PSTR + 16 * n + lr] = acc[n][r];
            }
        }
    }
    __syncthreads();

    // phase 3: parallel softmax (g-split rr 0..25 / 26..48) + mask + packed store
    {
        const int rr0 = g ? 26 : 0;
        const int nrr = g ? 23 : 26;
        float pv[26];
        #pragma unroll
        for (int i = 0; i < 26; ++i)
            pv[i] = (i < nrr) ? Pbuf[(rr0 + i) * PSTR + ch] : -1e30f;

        float mx = pv[0];
        #pragma unroll
        for (int i = 1; i < 26; ++i) mx = fmaxf(mx, pv[i]);
        ex_s[0][g][ch] = mx;
        __syncthreads();
        mx = fmaxf(ex_s[0][0][ch], ex_s[0][1][ch]);

        float s = 0.0f;
        #pragma unroll
        for (int i = 0; i < 26; ++i) {
            if (i < nrr) { pv[i] = __expf(pv[i] - mx); s += pv[i]; }
        }
        ex_s[1][g][ch] = s;
        __syncthreads();
        const float inv = 1.0f / (ex_s[1][0][ch] + ex_s[1][1][ch]);

        const int wb0 = (pos & 63) * (R * CH);
        float wv[26];
        #pragma unroll
        for (int i = 0; i < 26; ++i) {
            float val = 0.0f;
            if (i < nrr) {
                int rr  = rr0 + i;
                int rem = wb0 + ch * R + rr;
                int e2  = rem & (CH - 1);
                int j2  = (rem >> 7) % HH;
                int row = j2 + ii - 3;
                int col = e2 + jj - 3;
                bool valid = (row >= 0) && (row < HH) && (col >= 0) && (col < CH);
                val = valid ? pv[i] * inv : 0.0f;
            }
            wv[i] = val;
        }
        // pack pairs -> u32, store coalesced: wgt[pos][j][ch], g=0: j 0..12, g=1: j 13..24
        u32* wp = wgt + (size_t)pos * WGT_PP;
        const int nj = g ? 12 : 13;
        const int j0 = g ? 13 : 0;
        #pragma unroll
        for (int j = 0; j < 13; ++j) {
            if (j < nj) {
                u32 pk = (u32)(unsigned short)f2bf(wv[2 * j])
                       | ((u32)(unsigned short)f2bf(wv[2 * j + 1]) << 16);
                wp[(j0 + j) * CH + ch] = pk;
            }
        }
    }
}

// ---------- kernel B: apply weights, one block per (b,pos) ----------
__global__ __launch_bounds__(256, 6) void poatt_apply(
    const u32* __restrict__ x2,      // x as bf16 pairs
    const u32* __restrict__ wgt,     // packed weights [pos][j][ch]
    float* __restrict__ trb)         // (b,pos,ch)
{
    __shared__ __align__(16) float win[6400];
    __shared__ float part_s[CH];

    const int bid = blockIdx.x;
    const int pos = bid >> 3;
    const int b   = bid & 7;
    const int tid = threadIdx.x;
    const int ch  = tid & (CH - 1);
    const int g   = tid >> 7;

    const int q  = pos >> 6;
    const int ii = q / KS;
    const int jj = q % KS;
    const int winbase = (pos & 63) * (R * CH) + (ii - 3) * CH + (jj - 3);
    const int W0e = winbase & ~7;             // 8-elem aligned window start
    const int m2  = winbase & 7;
    const bool safe = (b > 0 || W0e >= 0) && (b < BS - 1 || W0e + 6400 <= XSTR);
    const int cbase = (b * XSTR + W0e) >> 3;  // u32x4-chunk index (aligned when safe)
    const unsigned short* x2s = reinterpret_cast<const unsigned short*>(x2);

    // stage 6400 bf16 elems -> fp32 LDS (800 chunks of 8)
    auto stage1 = [&](int cc) {
        float f[8];
        if (safe) {
            u32x4 v = reinterpret_cast<const u32x4*>(x2)[cbase + cc];
            #pragma unroll
            for (int k = 0; k < 4; ++k) {
                f[2 * k]     = bf2f_u(v[k] & 0xffffu);
                f[2 * k + 1] = bf2f_u(v[k] >> 16);
            }
        } else {
            #pragma unroll
            for (int k = 0; k < 8; ++k) {
                int e = b * XSTR + W0e + 8 * cc + k;
                e = e < 0 ? 0 : (e >= XTOT ? XTOT - 1 : e);   // masked (weight 0)
                f[k] = bf2f((short)x2s[e]);
            }
        }
        f32x4 lo = { f[0], f[1], f[2], f[3] };
        f32x4 hi = { f[4], f[5], f[6], f[7] };
        *reinterpret_cast<f32x4*>(&win[8 * cc])     = lo;
        *reinterpret_cast<f32x4*>(&win[8 * cc + 4]) = hi;
    };
    stage1(tid);
    stage1(tid + 256);
    stage1(tid + 512);
    if (tid < 32) stage1(tid + 768);

    // weights: 13 coalesced dwords/thread -> 26 bf16 (g=0: rr0..25, g=1: rr26..49)
    float pw[26];
    {
        const u32* wp = wgt + (size_t)pos * WGT_PP + (g ? 13 : 0) * CH + ch;
        const int nj = g ? 12 : 13;
        u32 wr[13];
        #pragma unroll
        for (int i = 0; i < 13; ++i) wr[i] = (i < nj) ? wp[i * CH] : 0u;
        #pragma unroll
        for (int i = 0; i < 13; ++i) {
            pw[2 * i]     = bf2f_u(wr[i] & 0xffffu);
            pw[2 * i + 1] = bf2f_u(wr[i] >> 16);
        }
    }
    __syncthreads();

    // compute: 26 (g=0) / 24 (g=1, incl zero pad rr49) fma from LDS
    const int base = m2 + ch * R + (g ? 26 : 0);
    const int nt   = g ? 24 : 26;
    float acc = 0.0f;
    #pragma unroll
    for (int i = 0; i < 26; ++i)
        if (i < nt) acc = fmaf(pw[i], win[base + i], acc);

    if (g) part_s[ch] = acc;
    __syncthreads();
    if (!g) trb[((size_t)b * NPOS + pos) * CH + ch] = acc + part_s[ch];
}

// ---------- transpose (b,pos,ch) -> (b,ch,pos) ----------
__global__ __launch_bounds__(256) void poatt_tr(
    const float* __restrict__ ws, float* __restrict__ out)
{
    __shared__ float t[64 * 129];
    const int blk = blockIdx.x;
    const int b   = blk / 49;
    const int p0  = (blk % 49) * 64;
    const int tid = threadIdx.x;

    const int chR = tid & 127, pR = tid >> 7;
    #pragma unroll
    for (int r = 0; r < 32; ++r) {
        int pl = pR + 2 * r;
        t[pl * 129 + chR] = ws[((size_t)b * NPOS + p0 + pl) * CH + chR];
    }
    __syncthreads();
    const int pW = tid & 63, chW0 = tid >> 6;
    #pragma unroll
    for (int c = 0; c < 32; ++c) {
        int chl = chW0 + 4 * c;
        out[((size_t)b * CH + chl) * NPOS + p0 + pW] = t[pW * 129 + chl];
    }
}

// ================= fallback: round-4 monolithic kernel =================
template<bool WS_W2, bool USE_WS>
__global__ __launch_bounds__(256, 4) void poatt_mono(
    const float* __restrict__ x,
    const float* __restrict__ W1, const float* __restrict__ b1,
    const float* __restrict__ W2,
    const short* __restrict__ wsH, const short* __restrict__ wsL,
    float* __restrict__ dst)
{
    __shared__ float rel_s[R][2];
    __shared__ __align__(16) char smem[2 * 64 * HSTR * 2];
    short* hidH = (short*)smem;
    short* hidL = hidH + 64 * HSTR;
    float* Pbuf = (float*)smem;

    const int pos = blockIdx.x;
    const int tid = threadIdx.x;
    const int ch  = tid & (CH - 1);
    const int g   = tid >> 7;

    const int q  = pos >> 6;
    const int ii = q / KS;
    const int jj = q % KS;

    if (tid < 2 * R) {
        const int e  = (tid >= R) ? 1 : 0;
        const int rr = tid - e * R;
        int F  = (pos * 2 + e) * R + rr;
        int ep = F & 1;
        int t  = F >> 1;
        int jp = t % HH; t /= HH;
        int a  = t % HH; t /= HH;
        int jc = t % KS;
        int ic = t / KS;
        int row = jp + ic - 3;
        int col = ep + jc - 3;
        float v = 0.0f;
        if (row >= 0 && row < HH && (col == 0 || col == 1)) {
            int f    = a * (HH * 2) + row * 2 + col;
            int cidx = f / NPOS;
            int p    = f - cidx * NPOS;
            int u    = (cidx == 0) ? (p / HH) : (p % HH);
            v = -3.0f + 6.0f * (float)u * (1.0f / 55.0f);
        }
        const float c0 = -3.0f + 6.0f * (float)(pos / HH) * (1.0f / 55.0f);
        const float c1 = -3.0f + 6.0f * (float)(pos % HH) * (1.0f / 55.0f);
        rel_s[rr][e] = v - ((e == 0) ? c0 : c1);
    }
    __syncthreads();

    {
        const float w10 = W1[ch];
        const float w11 = W1[CH + ch];
        const float bb  = b1[ch];
        for (int rr = g; rr < R; rr += 2) {
            float h = fmaf(rel_s[rr][0], w10, fmaf(rel_s[rr][1], w11, bb));
            h = fmaxf(h, 0.0f);
            short hi = f2bf(h);
            hidH[rr * HSTR + ch] = hi;
            hidL[rr * HSTR + ch] = f2bf(h - bf2f(hi));
        }
        for (int t = tid; t < 15 * HSTR; t += 256) {
            hidH[R * HSTR + t] = 0;
            hidL[R * HSTR + t] = 0;
        }
    }
    __syncthreads();

    {
        const int w  = tid >> 6;
        const int l  = tid & 63;
        const int lr = l & 15;
        const int kg = l >> 4;

        short8 aH[4], aL[4];
        const int abase = (16 * w + lr) * HSTR + kg * 8;
        #pragma unroll
        for (int kk = 0; kk < 4; ++kk) {
            aH[kk] = *reinterpret_cast<const short8*>(&hidH[abase + kk * 32]);
            aL[kk] = *reinterpret_cast<const short8*>(&hidL[abase + kk * 32]);
        }

        f32x4 acc[8];
        #pragma unroll
        for (int n = 0; n < 8; ++n) acc[n] = (f32x4)0.0f;

        #pragma unroll
        for (int n = 0; n < 8; ++n) {
            const int bcol = 16 * n + lr;
            #pragma unroll
            for (int kk = 0; kk < 4; ++kk) {
                short8 bH, bL;
                if (WS_W2) {
                    bH = *reinterpret_cast<const short8*>(wsH + bcol * CH + kk * 32 + kg * 8);
                    bL = *reinterpret_cast<const short8*>(wsL + bcol * CH + kk * 32 + kg * 8);
                } else {
                    #pragma unroll
                    for (int j = 0; j < 8; ++j) {
                        float ww = ((const float*)W2)[(kk * 32 + kg * 8 + j) * CH + bcol];
                        short hi = f2bf(ww);
                        bH[j] = hi;
                        bL[j] = f2bf(ww - bf2f(hi));
                    }
                }
                acc[n] = __builtin_amdgcn_mfma_f32_16x16x32_bf16(aL[kk], bH, acc[n], 0, 0, 0);
                acc[n] = __builtin_amdgcn_mfma_f32_16x16x32_bf16(aH[kk], bL, acc[n], 0, 0, 0);
                acc[n] = __builtin_amdgcn_mfma_f32_16x16x32_bf16(aH[kk], bH, acc[n], 0, 0, 0);
            }
        }
        __syncthreads();

        #pragma unroll
        for (int n = 0; n < 8; ++n) {
            #pragma unroll
            for (int r = 0; r < 4; ++r) {
                int rr = 16 * w + kg * 4 + r;
                if (rr < R) Pbuf[rr * PSTR + 16 * n + lr] = acc[n][r];
            }
        }
    }
    __syncthreads();

    if (tid < CH) {
        float p[R];
        #pragma unroll
        for (int rr = 0; rr < R; ++rr) p[rr] = Pbuf[rr * PSTR + tid];
        float mx = p[0];
        #pragma unroll
        for (int rr = 1; rr < R; ++rr) mx = fmaxf(mx, p[rr]);
        float s = 0.0f;
        #pragma unroll
        for (int rr = 0; rr < R; ++rr) { p[rr] = __expf(p[rr] - mx); s += p[rr]; }
        const float inv = 1.0f / s;
        const int wb0 = (pos & 63) * (R * CH);
        #pragma unroll
        for (int rr = 0; rr < R; ++rr) {
            int rem = wb0 + tid * R + rr;
            int e2  = rem & (CH - 1);
            int j2  = (rem >> 7) % HH;
            int row = j2 + ii - 3;
            int col = e2 + jj - 3;
            bool valid = (row >= 0) && (row < HH) && (col >= 0) && (col < CH);
            Pbuf[rr * PSTR + tid] = valid ? p[rr] * inv : 0.0f;
        }
    }
    __syncthreads();

    float p[R];
    #pragma unroll
    for (int rr = 0; rr < R; ++rr) p[rr] = Pbuf[rr * PSTR + ch];

    const int winbase = (pos & 63) * (R * CH) + (ii - 3) * CH + (jj - 3);
    const int base_t  = winbase + ch * R;

    #pragma unroll
    for (int bi = 0; bi < 4; ++bi) {
        const int b  = g * 4 + bi;
        const int ab = b * XSTR + base_t;
        const bool safe = (b > 0 || winbase >= 0) && (b < BS - 1 || winbase + R * CH <= XSTR);
        float acc = 0.0f;
        if (safe) {
            #pragma unroll
            for (int rr = 0; rr < R; ++rr) acc = fmaf(p[rr], x[ab + rr], acc);
        } else {
            #pragma unroll
            for (int rr = 0; rr < R; ++rr) {
                int a2 = ab + rr;
                a2 = a2 < 0 ? 0 : (a2 >= XTOT ? XTOT - 1 : a2);
                acc = fmaf(p[rr], x[a2], acc);
            }
        }
        if (USE_WS) dst[((size_t)b * NPOS + pos) * CH + ch] = acc;
        else        dst[((size_t)b * CH + ch) * NPOS + pos] = acc;
    }
}

extern "C" void kernel_launch(void* const* d_in, const int* in_sizes, int n_in,
                              void* d_out, int out_size, void* d_ws, size_t ws_size,
                              hipStream_t stream) {
    (void)in_sizes; (void)n_in; (void)out_size;
    const float* x  = (const float*)d_in[0];
    const float* W1 = (const float*)d_in[1];
    const float* b1 = (const float*)d_in[2];
    const float* W2 = (const float*)d_in[3];
    float* out = (float*)d_out;

    // ws layout: [W2T hi/lo 64KB][x2 bf16 6.125MB][wgt 38.3MB][trb 12.25MB]
    const size_t W2T_BYTES = 2u * CH * CH * sizeof(short);            //    65536
    const size_t X2_BYTES  = (size_t)XTOT * 2;                        //  6422528
    const size_t WGT_BYTES = (size_t)NPOS * WGT_PP * 4;               // 40140800
    const size_t TRB_BYTES = (size_t)BS * NPOS * CH * sizeof(float);  // 12845056
    const size_t FULL = W2T_BYTES + X2_BYTES + WGT_BYTES + TRB_BYTES; // 59473920

    short* wsH = (short*)d_ws;
    short* wsL = wsH + CH * CH;

    if (ws_size >= FULL) {
        u32*   x2  = (u32*)((char*)d_ws + W2T_BYTES);
        u32*   wgt = (u32*)((char*)d_ws + W2T_BYTES + X2_BYTES);
        float* trb = (float*)((char*)d_ws + W2T_BYTES + X2_BYTES + WGT_BYTES);

        poatt_prep<<<dim3(64), dim3(256), 0, stream>>>(W2, wsH, wsL);
        poatt_cvt<<<dim3(XTOT / (256 * 8)), dim3(256), 0, stream>>>(x, x2);
        poatt_wgt<<<dim3(NPOS), dim3(256), 0, stream>>>(W1, b1, wsH, wsL, wgt);
        poatt_apply<<<dim3(NPOS * BS), dim3(256), 0, stream>>>(x2, wgt, trb);
        poatt_tr<<<dim3(BS * 49), dim3(256), 0, stream>>>(trb, out);
    } else if (ws_size >= W2T_BYTES + TRB_BYTES) {
        float* trb = (float*)((char*)d_ws + W2T_BYTES);
        poatt_prep<<<dim3(64), dim3(256), 0, stream>>>(W2, wsH, wsL);
        poatt_mono<true, true><<<dim3(NPOS), dim3(256), 0, stream>>>(
            x, W1, b1, W2, wsH, wsL, trb);
        poatt_tr<<<dim3(BS * 49), dim3(256), 0, stream>>>(trb, out);
    } else if (ws_size >= W2T_BYTES) {
        poatt_prep<<<dim3(64), dim3(256), 0, stream>>>(W2, wsH, wsL);
        poatt_mono<true, false><<<dim3(NPOS), dim3(256), 0, stream>>>(
            x, W1, b1, W2, wsH, wsL, out);
    } else {
        poatt_mono<false, false><<<dim3(NPOS), dim3(256), 0, stream>>>(
            x, W1, b1, W2, nullptr, nullptr, out);
    }
}

// Round 7
// 97.777 us; speedup vs baseline: 1.8029x; 1.8029x over previous
//
#include <hip/hip_runtime.h>

#define CH   128
#define KS   7
#define R    49
#define HH   56
#define NPOS 3136
#define BS   8
#define XSTR 401408
#define XTOT (BS*XSTR)

typedef short short8 __attribute__((ext_vector_type(8)));
typedef float f32x4  __attribute__((ext_vector_type(4)));
typedef unsigned int u32;
typedef u32 u32x4 __attribute__((ext_vector_type(4)));

__device__ __forceinline__ short f2bf(float f) {            // RNE fp32->bf16
    unsigned u = __float_as_uint(f);
    u += 0x7fffu + ((u >> 16) & 1u);
    return (short)(u >> 16);
}
__device__ __forceinline__ float bf2f(short s) {
    return __uint_as_float(((unsigned)(unsigned short)s) << 16);
}
__device__ __forceinline__ float bf2f_u(u32 lo16) {
    return __uint_as_float(lo16 << 16);
}

#define HSTR 136            // hid LDS row stride (bf16 elems)
#define PSTR 132            // P LDS row stride (fp32) - mono fallback only
#define WGT_PP 3200         // u32 per pos: 25 j-pairs * 128 ch

// ---------- prep: W2 (fp32 [m][ch]) -> W2^T hi/lo bf16 ([ch][m]) ----------
__global__ __launch_bounds__(256) void poatt_prep(
    const float* __restrict__ W2, short* __restrict__ wsH, short* __restrict__ wsL)
{
    int t = blockIdx.x * 256 + threadIdx.x;
    int k = t >> 7, ch = t & 127;
    float w = W2[k * CH + ch];
    short hi = f2bf(w);
    wsH[ch * CH + k] = hi;
    wsL[ch * CH + k] = f2bf(w - bf2f(hi));
}

// ---------- cvt: x fp32 -> bf16 pairs ----------
__global__ __launch_bounds__(256) void poatt_cvt(
    const float* __restrict__ x, u32* __restrict__ x2)
{
    int t = blockIdx.x * 256 + threadIdx.x;      // 1568 blocks
    const float4* xv = reinterpret_cast<const float4*>(x);
    float4 a = xv[2 * t], b = xv[2 * t + 1];
    u32x4 o;
    o[0] = (u32)(unsigned short)f2bf(a.x) | ((u32)(unsigned short)f2bf(a.y) << 16);
    o[1] = (u32)(unsigned short)f2bf(a.z) | ((u32)(unsigned short)f2bf(a.w) << 16);
    o[2] = (u32)(unsigned short)f2bf(b.x) | ((u32)(unsigned short)f2bf(b.y) << 16);
    o[3] = (u32)(unsigned short)f2bf(b.z) | ((u32)(unsigned short)f2bf(b.w) << 16);
    reinterpret_cast<u32x4*>(x2)[t] = o;
}

// ---------- kernel A: softmax weights per pos -> packed bf16 [pos][j][ch] ----------
// wave w owns ch [32w,32w+32): full 49-rr column -> in-register softmax, 1 barrier.
__global__ __launch_bounds__(256, 4) void poatt_wgt(
    const float* __restrict__ W1, const float* __restrict__ b1,
    const short* __restrict__ wsH, const short* __restrict__ wsL,
    u32* __restrict__ wgt)
{
    __shared__ float rel_s[R][2];
    __shared__ __align__(16) short hid_s[64 * HSTR];   // 17408 B, bf16

    const int pos = blockIdx.x;
    const int tid = threadIdx.x;
    const int ch  = tid & (CH - 1);
    const int g   = tid >> 7;

    const int q  = pos >> 6;
    const int ii = q / KS;
    const int jj = q % KS;

    // phase 0: rel
    if (tid < 2 * R) {
        const int e  = (tid >= R) ? 1 : 0;
        const int rr = tid - e * R;
        int F  = (pos * 2 + e) * R + rr;
        int ep = F & 1;
        int t  = F >> 1;
        int jp = t % HH; t /= HH;
        int a  = t % HH; t /= HH;
        int jc = t % KS;
        int ic = t / KS;
        int row = jp + ic - 3;
        int col = ep + jc - 3;
        float v = 0.0f;
        if (row >= 0 && row < HH && (col == 0 || col == 1)) {
            int f    = a * (HH * 2) + row * 2 + col;
            int cidx = f / NPOS;
            int p    = f - cidx * NPOS;
            int u    = (cidx == 0) ? (p / HH) : (p % HH);
            v = -3.0f + 6.0f * (float)u * (1.0f / 55.0f);
        }
        const float c0 = -3.0f + 6.0f * (float)(pos / HH) * (1.0f / 55.0f);
        const float c1 = -3.0f + 6.0f * (float)(pos % HH) * (1.0f / 55.0f);
        rel_s[rr][e] = v - ((e == 0) ? c0 : c1);
    }
    __syncthreads();

    // phase 1: hid = relu(rel@W1+b1) -> single bf16 LDS
    {
        const float w10 = W1[ch];
        const float w11 = W1[CH + ch];
        const float bb  = b1[ch];
        for (int rr = g; rr < R; rr += 2) {
            float h = fmaf(rel_s[rr][0], w10, fmaf(rel_s[rr][1], w11, bb));
            hid_s[rr * HSTR + ch] = f2bf(fmaxf(h, 0.0f));
        }
        for (int t = tid; t < 15 * HSTR; t += 256) hid_s[R * HSTR + t] = 0;
    }
    __syncthreads();

    // phase 2: P columns [32w,32w+32) via 2-term MFMA (A bf16, B hi/lo)
    const int w  = tid >> 6;
    const int l  = tid & 63;
    const int lr = l & 15;
    const int kg = l >> 4;

    f32x4 acc[4][2];
    #pragma unroll
    for (int mt = 0; mt < 4; ++mt) { acc[mt][0] = (f32x4)0.0f; acc[mt][1] = (f32x4)0.0f; }

    #pragma unroll
    for (int np = 0; np < 2; ++np) {
        const int bcol = 32 * w + 16 * np + lr;
        short8 bH[4], bL[4];
        #pragma unroll
        for (int kk = 0; kk < 4; ++kk) {
            bH[kk] = *reinterpret_cast<const short8*>(wsH + bcol * CH + kk * 32 + kg * 8);
            bL[kk] = *reinterpret_cast<const short8*>(wsL + bcol * CH + kk * 32 + kg * 8);
        }
        #pragma unroll
        for (int mt = 0; mt < 4; ++mt) {
            #pragma unroll
            for (int kk = 0; kk < 4; ++kk) {
                short8 a = *reinterpret_cast<const short8*>(
                    &hid_s[(16 * mt + lr) * HSTR + kk * 32 + kg * 8]);
                acc[mt][np] = __builtin_amdgcn_mfma_f32_16x16x32_bf16(a, bH[kk], acc[mt][np], 0, 0, 0);
                acc[mt][np] = __builtin_amdgcn_mfma_f32_16x16x32_bf16(a, bL[kk], acc[mt][np], 0, 0, 0);
            }
        }
    }

    // phase 3: in-register softmax over rr (shuffle across kg) + mask + packed store
    const int wb0 = (pos & 63) * (R * CH);
    u32* wp = wgt + (size_t)pos * WGT_PP;
    float wv[4][4];

    #pragma unroll
    for (int np = 0; np < 2; ++np) {
        const int chh = 32 * w + 16 * np + lr;

        float mx = -1e30f;
        #pragma unroll
        for (int mt = 0; mt < 4; ++mt)
            #pragma unroll
            for (int r = 0; r < 4; ++r) {
                int rr = 16 * mt + 4 * kg + r;
                if (rr < R) mx = fmaxf(mx, acc[mt][np][r]);
            }
        mx = fmaxf(mx, __shfl_xor(mx, 16));
        mx = fmaxf(mx, __shfl_xor(mx, 32));

        float s = 0.0f;
        #pragma unroll
        for (int mt = 0; mt < 4; ++mt)
            #pragma unroll
            for (int r = 0; r < 4; ++r) {
                int rr = 16 * mt + 4 * kg + r;
                float e = (rr < R) ? __expf(acc[mt][np][r] - mx) : 0.0f;
                wv[mt][r] = e;
                s += e;
            }
        s += __shfl_xor(s, 16);
        s += __shfl_xor(s, 32);
        const float inv = 1.0f / s;

        #pragma unroll
        for (int mt = 0; mt < 4; ++mt)
            #pragma unroll
            for (int r = 0; r < 4; ++r) {
                int rr = 16 * mt + 4 * kg + r;
                if (rr < R) {
                    int rem = wb0 + chh * R + rr;
                    int e2  = rem & (CH - 1);
                    int j2  = (rem >> 7) % HH;
                    int row = j2 + ii - 3;
                    int col = e2 + jj - 3;
                    bool valid = (row >= 0) && (row < HH) && (col >= 0) && (col < CH);
                    wv[mt][r] = valid ? wv[mt][r] * inv : 0.0f;
                }
            }

        #pragma unroll
        for (int mt = 0; mt < 4; ++mt)
            #pragma unroll
            for (int jp = 0; jp < 2; ++jp) {
                int j = 8 * mt + 2 * kg + jp;
                if (j <= 24) {
                    u32 pk = (u32)(unsigned short)f2bf(wv[mt][2 * jp])
                           | ((u32)(unsigned short)f2bf(wv[mt][2 * jp + 1]) << 16);
                    wp[j * CH + chh] = pk;
                }
            }
    }
}

// ---------- kernel B: apply weights, one block per pos, 8 batches ----------
__global__ __launch_bounds__(256, 4) void poatt_apply(
    const u32* __restrict__ x2,      // x as bf16 pairs
    const u32* __restrict__ wgt,     // packed weights [pos][j][ch]
    float* __restrict__ trb)         // (b,pos,ch)
{
    __shared__ __align__(16) float win[6400];
    __shared__ float part_s[CH];

    const int pos = blockIdx.x;
    const int tid = threadIdx.x;
    const int ch  = tid & (CH - 1);
    const int g   = tid >> 7;

    const int q  = pos >> 6;
    const int ii = q / KS;
    const int jj = q % KS;
    const int winbase = (pos & 63) * (R * CH) + (ii - 3) * CH + (jj - 3);
    const int W0e = winbase & ~7;             // 8-elem aligned window start
    const int m2  = winbase & 7;
    const unsigned short* x2s = reinterpret_cast<const unsigned short*>(x2);
    const u32x4* x2v = reinterpret_cast<const u32x4*>(x2);

    // weights: 13 coalesced dwords/thread -> 26 bf16 (g=0: rr0..25, g=1: rr26..49)
    float pw[26];
    {
        const u32* wp = wgt + (size_t)pos * WGT_PP + (g ? 13 : 0) * CH + ch;
        const int nj = g ? 12 : 13;
        u32 wr[13];
        #pragma unroll
        for (int i = 0; i < 13; ++i) wr[i] = (i < nj) ? wp[i * CH] : 0u;
        #pragma unroll
        for (int i = 0; i < 13; ++i) {
            pw[2 * i]     = bf2f_u(wr[i] & 0xffffu);
            pw[2 * i + 1] = bf2f_u(wr[i] >> 16);
        }
    }

    u32x4 v[4];                                  // staged chunks (8 bf16 each)
    auto ld = [&](int b) {
        const bool safe = (b > 0 || W0e >= 0) && (b < BS - 1 || W0e + 6400 <= XSTR);
        if (safe) {
            const int cbase = (b * XSTR + W0e) >> 3;
            v[0] = x2v[cbase + tid];
            v[1] = x2v[cbase + tid + 256];
            v[2] = x2v[cbase + tid + 512];
            if (tid < 32) v[3] = x2v[cbase + tid + 768];
        } else {
            #pragma unroll
            for (int j = 0; j < 4; ++j) {
                if (j == 3 && tid >= 32) break;
                int cc = tid + 256 * j;
                u32x4 o;
                #pragma unroll
                for (int k = 0; k < 4; ++k) {
                    int e0 = b * XSTR + W0e + 8 * cc + 2 * k;
                    int a0 = e0;     a0 = a0 < 0 ? 0 : (a0 >= XTOT ? XTOT - 1 : a0);
                    int a1 = e0 + 1; a1 = a1 < 0 ? 0 : (a1 >= XTOT ? XTOT - 1 : a1);
                    o[k] = (u32)x2s[a0] | ((u32)x2s[a1] << 16);
                }
                v[j] = o;
            }
        }
    };
    auto st = [&]() {
        #pragma unroll
        for (int j = 0; j < 4; ++j) {
            if (j == 3 && tid >= 32) break;
            int cc = tid + 256 * j;
            f32x4 lo, hi;
            #pragma unroll
            for (int k = 0; k < 4; ++k) {
                float f0 = bf2f_u(v[j][k] & 0xffffu);
                float f1 = bf2f_u(v[j][k] >> 16);
                if (k < 2) { lo[2 * k] = f0; lo[2 * k + 1] = f1; }
                else       { hi[2 * (k - 2)] = f0; hi[2 * (k - 2) + 1] = f1; }
            }
            *reinterpret_cast<f32x4*>(&win[8 * cc])     = lo;
            *reinterpret_cast<f32x4*>(&win[8 * cc + 4]) = hi;
        }
    };

    ld(0);
    st();
    __syncthreads();

    const int base = m2 + ch * R + (g ? 26 : 0);
    const int nt   = g ? 24 : 26;

    for (int b = 0; b < BS; ++b) {
        if (b + 1 < BS) ld(b + 1);               // issue early (T14)

        float acc = 0.0f;
        #pragma unroll
        for (int i = 0; i < 26; ++i)
            if (i < nt) acc = fmaf(pw[i], win[base + i], acc);
        if (g) part_s[ch] = acc;
        __syncthreads();                          // win reads done + part_s visible
        if (!g) trb[((size_t)b * NPOS + pos) * CH + ch] = acc + part_s[ch];
        if (b + 1 < BS) {
            st();                                 // write late
        }
        __syncthreads();                          // win ready for next batch
    }
}

// ---------- transpose (b,pos,ch) -> (b,ch,pos) ----------
__global__ __launch_bounds__(256) void poatt_tr(
    const float* __restrict__ ws, float* __restrict__ out)
{
    __shared__ float t[64 * 129];
    const int blk = blockIdx.x;
    const int b   = blk / 49;
    const int p0  = (blk % 49) * 64;
    const int tid = threadIdx.x;

    const int chR = tid & 127, pR = tid >> 7;
    #pragma unroll
    for (int r = 0; r < 32; ++r) {
        int pl = pR + 2 * r;
        t[pl * 129 + chR] = ws[((size_t)b * NPOS + p0 + pl) * CH + chR];
    }
    __syncthreads();
    const int pW = tid & 63, chW0 = tid >> 6;
    #pragma unroll
    for (int c = 0; c < 32; ++c) {
        int chl = chW0 + 4 * c;
        out[((size_t)b * CH + chl) * NPOS + p0 + pW] = t[pW * 129 + chl];
    }
}

// ================= fallback: monolithic kernel (round-4 proven) =================
template<bool WS_W2, bool USE_WS>
__global__ __launch_bounds__(256, 4) void poatt_mono(
    const float* __restrict__ x,
    const float* __restrict__ W1, const float* __restrict__ b1,
    const float* __restrict__ W2,
    const short* __restrict__ wsH, const short* __restrict__ wsL,
    float* __restrict__ dst)
{
    __shared__ float rel_s[R][2];
    __shared__ __align__(16) char smem[2 * 64 * HSTR * 2];
    short* hidH = (short*)smem;
    short* hidL = hidH + 64 * HSTR;
    float* Pbuf = (float*)smem;

    const int pos = blockIdx.x;
    const int tid = threadIdx.x;
    const int ch  = tid & (CH - 1);
    const int g   = tid >> 7;

    const int q  = pos >> 6;
    const int ii = q / KS;
    const int jj = q % KS;

    if (tid < 2 * R) {
        const int e  = (tid >= R) ? 1 : 0;
        const int rr = tid - e * R;
        int F  = (pos * 2 + e) * R + rr;
        int ep = F & 1;
        int t  = F >> 1;
        int jp = t % HH; t /= HH;
        int a  = t % HH; t /= HH;
        int jc = t % KS;
        int ic = t / KS;
        int row = jp + ic - 3;
        int col = ep + jc - 3;
        float v = 0.0f;
        if (row >= 0 && row < HH && (col == 0 || col == 1)) {
            int f    = a * (HH * 2) + row * 2 + col;
            int cidx = f / NPOS;
            int p    = f - cidx * NPOS;
            int u    = (cidx == 0) ? (p / HH) : (p % HH);
            v = -3.0f + 6.0f * (float)u * (1.0f / 55.0f);
        }
        const float c0 = -3.0f + 6.0f * (float)(pos / HH) * (1.0f / 55.0f);
        const float c1 = -3.0f + 6.0f * (float)(pos % HH) * (1.0f / 55.0f);
        rel_s[rr][e] = v - ((e == 0) ? c0 : c1);
    }
    __syncthreads();

    {
        const float w10 = W1[ch];
        const float w11 = W1[CH + ch];
        const float bb  = b1[ch];
        for (int rr = g; rr < R; rr += 2) {
            float h = fmaf(rel_s[rr][0], w10, fmaf(rel_s[rr][1], w11, bb));
            h = fmaxf(h, 0.0f);
            short hi = f2bf(h);
            hidH[rr * HSTR + ch] = hi;
            hidL[rr * HSTR + ch] = f2bf(h - bf2f(hi));
        }
        for (int t = tid; t < 15 * HSTR; t += 256) {
            hidH[R * HSTR + t] = 0;
            hidL[R * HSTR + t] = 0;
        }
    }
    __syncthreads();

    {
        const int w  = tid >> 6;
        const int l  = tid & 63;
        const int lr = l & 15;
        const int kg = l >> 4;

        short8 aH[4], aL[4];
        const int abase = (16 * w + lr) * HSTR + kg * 8;
        #pragma unroll
        for (int kk = 0; kk < 4; ++kk) {
            aH[kk] = *reinterpret_cast<const short8*>(&hidH[abase + kk * 32]);
            aL[kk] = *reinterpret_cast<const short8*>(&hidL[abase + kk * 32]);
        }

        f32x4 acc[8];
        #pragma unroll
        for (int n = 0; n < 8; ++n) acc[n] = (f32x4)0.0f;

        #pragma unroll
        for (int n = 0; n < 8; ++n) {
            const int bcol = 16 * n + lr;
            #pragma unroll
            for (int kk = 0; kk < 4; ++kk) {
                short8 bH, bL;
                if (WS_W2) {
                    bH = *reinterpret_cast<const short8*>(wsH + bcol * CH + kk * 32 + kg * 8);
                    bL = *reinterpret_cast<const short8*>(wsL + bcol * CH + kk * 32 + kg * 8);
                } else {
                    #pragma unroll
                    for (int j = 0; j < 8; ++j) {
                        float ww = ((const float*)W2)[(kk * 32 + kg * 8 + j) * CH + bcol];
                        short hi = f2bf(ww);
                        bH[j] = hi;
                        bL[j] = f2bf(ww - bf2f(hi));
                    }
                }
                acc[n] = __builtin_amdgcn_mfma_f32_16x16x32_bf16(aL[kk], bH, acc[n], 0, 0, 0);
                acc[n] = __builtin_amdgcn_mfma_f32_16x16x32_bf16(aH[kk], bL, acc[n], 0, 0, 0);
                acc[n] = __builtin_amdgcn_mfma_f32_16x16x32_bf16(aH[kk], bH, acc[n], 0, 0, 0);
            }
        }
        __syncthreads();

        #pragma unroll
        for (int n = 0; n < 8; ++n) {
            #pragma unroll
            for (int r = 0; r < 4; ++r) {
                int rr = 16 * w + kg * 4 + r;
                if (rr < R) Pbuf[rr * PSTR + 16 * n + lr] = acc[n][r];
            }
        }
    }
    __syncthreads();

    if (tid < CH) {
        float p[R];
        #pragma unroll
        for (int rr = 0; rr < R; ++rr) p[rr] = Pbuf[rr * PSTR + tid];
        float mx = p[0];
        #pragma unroll
        for (int rr = 1; rr < R; ++rr) mx = fmaxf(mx, p[rr]);
        float s = 0.0f;
        #pragma unroll
        for (int rr = 0; rr < R; ++rr) { p[rr] = __expf(p[rr] - mx); s += p[rr]; }
        const float inv = 1.0f / s;
        const int wb0 = (pos & 63) * (R * CH);
        #pragma unroll
        for (int rr = 0; rr < R; ++rr) {
            int rem = wb0 + tid * R + rr;
            int e2  = rem & (CH - 1);
            int j2  = (rem >> 7) % HH;
            int row = j2 + ii - 3;
            int col = e2 + jj - 3;
            bool valid = (row >= 0) && (row < HH) && (col >= 0) && (col < CH);
            Pbuf[rr * PSTR + tid] = valid ? p[rr] * inv : 0.0f;
        }
    }
    __syncthreads();

    float p[R];
    #pragma unroll
    for (int rr = 0; rr < R; ++rr) p[rr] = Pbuf[rr * PSTR + ch];

    const int winbase = (pos & 63) * (R * CH) + (ii - 3) * CH + (jj - 3);
    const int base_t  = winbase + ch * R;

    #pragma unroll
    for (int bi = 0; bi < 4; ++bi) {
        const int b  = g * 4 + bi;
        const int ab = b * XSTR + base_t;
        const bool safe = (b > 0 || winbase >= 0) && (b < BS - 1 || winbase + R * CH <= XSTR);
        float acc = 0.0f;
        if (safe) {
            #pragma unroll
            for (int rr = 0; rr < R; ++rr) acc = fmaf(p[rr], x[ab + rr], acc);
        } else {
            #pragma unroll
            for (int rr = 0; rr < R; ++rr) {
                int a2 = ab + rr;
                a2 = a2 < 0 ? 0 : (a2 >= XTOT ? XTOT - 1 : a2);
                acc = fmaf(p[rr], x[a2], acc);
            }
        }
        if (USE_WS) dst[((size_t)b * NPOS + pos) * CH + ch] = acc;
        else        dst[((size_t)b * CH + ch) * NPOS + pos] = acc;
    }
}

extern "C" void kernel_launch(void* const* d_in, const int* in_sizes, int n_in,
                              void* d_out, int out_size, void* d_ws, size_t ws_size,
                              hipStream_t stream) {
    (void)in_sizes; (void)n_in; (void)out_size;
    const float* x  = (const float*)d_in[0];
    const float* W1 = (const float*)d_in[1];
    const float* b1 = (const float*)d_in[2];
    const float* W2 = (const float*)d_in[3];
    float* out = (float*)d_out;

    // ws layout: [W2T hi/lo 64KB][x2 bf16 6.125MB][wgt 38.3MB][trb 12.25MB]
    const size_t W2T_BYTES = 2u * CH * CH * sizeof(short);            //    65536
    const size_t X2_BYTES  = (size_t)XTOT * 2;                        //  6422528
    const size_t WGT_BYTES = (size_t)NPOS * WGT_PP * 4;               // 40140800
    const size_t TRB_BYTES = (size_t)BS * NPOS * CH * sizeof(float);  // 12845056
    const size_t FULL = W2T_BYTES + X2_BYTES + WGT_BYTES + TRB_BYTES; // 59473920

    short* wsH = (short*)d_ws;
    short* wsL = wsH + CH * CH;

    if (ws_size >= FULL) {
        u32*   x2  = (u32*)((char*)d_ws + W2T_BYTES);
        u32*   wgt = (u32*)((char*)d_ws + W2T_BYTES + X2_BYTES);
        float* trb = (float*)((char*)d_ws + W2T_BYTES + X2_BYTES + WGT_BYTES);

        poatt_prep<<<dim3(64), dim3(256), 0, stream>>>(W2, wsH, wsL);
        poatt_cvt<<<dim3(XTOT / (256 * 8)), dim3(256), 0, stream>>>(x, x2);
        poatt_wgt<<<dim3(NPOS), dim3(256), 0, stream>>>(W1, b1, wsH, wsL, wgt);
        poatt_apply<<<dim3(NPOS), dim3(256), 0, stream>>>(x2, wgt, trb);
        poatt_tr<<<dim3(BS * 49), dim3(256), 0, stream>>>(trb, out);
    } else if (ws_size >= W2T_BYTES + TRB_BYTES) {
        float* trb = (float*)((char*)d_ws + W2T_BYTES);
        poatt_prep<<<dim3(64), dim3(256), 0, stream>>>(W2, wsH, wsL);
        poatt_mono<true, true><<<dim3(NPOS), dim3(256), 0, stream>>>(
            x, W1, b1, W2, wsH, wsL, trb);
        poatt_tr<<<dim3(BS * 49), dim3(256), 0, stream>>>(trb, out);
    } else if (ws_size >= W2T_BYTES) {
        poatt_prep<<<dim3(64), dim3(256), 0, stream>>>(W2, wsH, wsL);
        poatt_mono<true, false><<<dim3(NPOS), dim3(256), 0, stream>>>(
            x, W1, b1, W2, wsH, wsL, out);
    } else {
        poatt_mono<false, false><<<dim3(NPOS), dim3(256), 0, stream>>>(
            x, W1, b1, W2, nullptr, nullptr, out);
    }
}